// Round 2
// baseline (100.149 us; speedup 1.0000x reference)
//
#include <hip/hip_runtime.h>

// SparseAttention: B=4, M=4096, N=4096, D=128, W=128, fp32 in/out.
// Round 18: kernel is gathered-bytes-bound (~16 B/lane-cyc vector-memory
// ceiling; 400 MB gathered ≈ 41 µs matches measurement). Byte-cut round:
//  - Screen K in int4 (unsigned nibbles, bias +8, sdot4 + (-8*sum_q)
//    correction; Q stays int8): 64 B/row = 1 cache line, 268->134 MB.
//    Noise sigma~1.4 -> looser EPS (2.3e-7), n ~10 -> ~17.
//  - Unified 32-slot register rescore (8 slots/lane, t*4+r4): the old
//    n>16 LDS fallback ran ~20% of rows; now only n>32 (~8%) falls back.
//  - V gathered AFTER softmax, only where weight >= 3e-5 (~9 rows):
//    throughput-bound => lost latency overlap is free; 63->~42 MB.
// NO VGPR cap (R12), hoisted-load idiom kept (R11), screen/ballot idiom
// from R13 kept otherwise.

typedef __attribute__((ext_vector_type(2))) _Float16 half2v;
typedef __attribute__((ext_vector_type(8))) _Float16 half8;

constexpr int Bc = 4, Mc = 4096, Nc = 4096, Dc = 128, Wc = 128;
constexpr size_t KV_ELEMS = (size_t)Bc * Nc * Dc;   // 2,097,152 per tensor
constexpr float EPS_SCREEN = 2.3e-7f;    // int4-noise-widened keep threshold
constexpr float WEPS = 3e-5f;            // V-gather weight filter
constexpr float QS   = 127.f / 6.f;      // q int8 scale
constexpr float QK4  = 7.f / 3.f;        // k int4 scale (clip 3 sigma)
constexpr float INV_S48 = (6.f / 127.f) * (3.f / 7.f);

// ---- pre-pass: K fp32 -> fp16 + packed unsigned int4 (bias +8); V -> fp16 ----
__global__ __launch_bounds__(256) void cvt_kernel(
    const float* __restrict__ k3d, const float* __restrict__ v3d,
    _Float16* __restrict__ kh, unsigned int* __restrict__ k4p,
    _Float16* __restrict__ vh)
{
    const size_t i = ((size_t)blockIdx.x * blockDim.x + threadIdx.x) * 8;
    if (i >= KV_ELEMS) return;
    const float4 ka = *reinterpret_cast<const float4*>(k3d + i);
    const float4 kb = *reinterpret_cast<const float4*>(k3d + i + 4);
    half8 hk;
    hk[0]=(_Float16)ka.x; hk[1]=(_Float16)ka.y; hk[2]=(_Float16)ka.z; hk[3]=(_Float16)ka.w;
    hk[4]=(_Float16)kb.x; hk[5]=(_Float16)kb.y; hk[6]=(_Float16)kb.z; hk[7]=(_Float16)kb.w;
    *reinterpret_cast<half8*>(kh + i) = hk;
    const float f[8] = {ka.x, ka.y, ka.z, ka.w, kb.x, kb.y, kb.z, kb.w};
    unsigned int w4 = 0;
    #pragma unroll
    for (int jj = 0; jj < 8; ++jj) {
        int v = __float2int_rn(f[jj] * QK4);
        v = max(-7, min(7, v));
        w4 |= ((unsigned int)(v + 8)) << (4 * jj);   // unsigned nibble, bias +8
    }
    k4p[i / 8] = w4;

    const float4 va = *reinterpret_cast<const float4*>(v3d + i);
    const float4 vb = *reinterpret_cast<const float4*>(v3d + i + 4);
    half8 hv;
    hv[0]=(_Float16)va.x; hv[1]=(_Float16)va.y; hv[2]=(_Float16)va.z; hv[3]=(_Float16)va.w;
    hv[4]=(_Float16)vb.x; hv[5]=(_Float16)vb.y; hv[6]=(_Float16)vb.z; hv[7]=(_Float16)vb.w;
    *reinterpret_cast<half8*>(vh + i) = hv;
}

__device__ __forceinline__ float dot8_f16(const half8& qv, const half8& kv) {
    const half2v q0 = {qv[0], qv[1]}, q1 = {qv[2], qv[3]},
                 q2 = {qv[4], qv[5]}, q3 = {qv[6], qv[7]};
    const half2v k0 = {kv[0], kv[1]}, k1 = {kv[2], kv[3]},
                 k2 = {kv[4], kv[5]}, k3 = {kv[6], kv[7]};
    float p = __builtin_amdgcn_fdot2(q0, k0, 0.f, false);
    p = __builtin_amdgcn_fdot2(q1, k1, p, false);
    p = __builtin_amdgcn_fdot2(q2, k2, p, false);
    p = __builtin_amdgcn_fdot2(q3, k3, p, false);
    return p;
}

__device__ __forceinline__ int sd4(int a, int b, int c) {
    return __builtin_amdgcn_sdot4(a, b, c, false);
}

__global__ __launch_bounds__(128) void sparse_attn_r18(
    const float*        __restrict__ q3d,
    const _Float16*     __restrict__ kh,
    const unsigned int* __restrict__ k4p,
    const _Float16*     __restrict__ vh,
    const int*          __restrict__ cidx,
    float*              __restrict__ out)
{
    // 2 independent waves per block, one m-row each; XCD-pinned batches.
    const int blk = blockIdx.x;               // 0..8191
    const int u   = threadIdx.x >> 6;         // wave 0/1
    const int j   = threadIdx.x & 63;         // lane
    const int xcd = blk & 7;
    const int b   = xcd >> 1;
    const int m   = ((blk >> 3) << 2) | ((xcd & 1) << 1) | u;

    __shared__ __align__(16) _Float16 qsh[2][Dc];
    __shared__ __align__(16) unsigned int qpk[2][32]; // q int8, even/odd dword pairs
    __shared__ int   cs[2][Wc];
    __shared__ float part[2][4][144];     // screen partials; stride 144 -> 2-way free
    __shared__ int   widx[2][Wc];
    __shared__ float lswp[2][Wc];         // fallback (n>32) logits/weights only

    {
        const size_t qb = ((size_t)b * Mc + m) * Dc;
        const float2 qf = *reinterpret_cast<const float2*>(q3d + qb + 2 * j);
        half2v qh2 = {(_Float16)qf.x, (_Float16)qf.y};
        *reinterpret_cast<half2v*>(&qsh[u][2 * j]) = qh2;
        int v0 = __float2int_rn(qf.x * QS); v0 = max(-127, min(127, v0));
        int v1 = __float2int_rn(qf.y * QS); v1 = max(-127, min(127, v1));
        // elem 2j -> group g=j>>2 even slot (j&3); elem 2j+1 -> odd slot
        signed char* qb8 = reinterpret_cast<signed char*>(qpk[u]);
        qb8[(j >> 2) * 8 + (j & 3)]     = (signed char)v0;
        qb8[(j >> 2) * 8 + 4 + (j & 3)] = (signed char)v1;
        cs[u][j]      = cidx[m * Wc + j];
        cs[u][64 + j] = cidx[m * Wc + 64 + j];
        widx[u][j] = 0; widx[u][64 + j] = 0;   // safety for predicated addr calc
    }
    __builtin_amdgcn_wave_barrier();

    // ---- Screen: int4 rows (64 B = 1 line), 16 rows/instr, 8 hoisted gathers ----
    const int c4  = j & 3;     // 16-B chunk (elems c4*32..+31)
    const int r16 = j >> 2;    // row-in-volley 0..15
    const uint4* kb4 = reinterpret_cast<const uint4*>(k4p) + (size_t)b * Nc * (Dc / 32);
    const uint4 qda = *reinterpret_cast<const uint4*>(&qpk[u][c4 * 8]);
    const uint4 qdb = *reinterpret_cast<const uint4*>(&qpk[u][c4 * 8 + 4]);
    // signed sum of q int8 over this 32-elem chunk (for the +8-bias correction)
    int qs = sd4((int)qda.x, 0x01010101, 0);
    qs = sd4((int)qda.y, 0x01010101, qs);
    qs = sd4((int)qda.z, 0x01010101, qs);
    qs = sd4((int)qda.w, 0x01010101, qs);
    qs = sd4((int)qdb.x, 0x01010101, qs);
    qs = sd4((int)qdb.y, 0x01010101, qs);
    qs = sd4((int)qdb.z, 0x01010101, qs);
    qs = sd4((int)qdb.w, 0x01010101, qs);

    int rb[8];
    #pragma unroll
    for (int v = 0; v < 8; ++v) rb[v] = cs[u][v * 16 + r16] * 4 + c4;  // uint4 units
    uint4 kr[8];
    #pragma unroll
    for (int v = 0; v < 8; ++v) kr[v] = kb4[rb[v]];
    #pragma unroll
    for (int v = 0; v < 8; ++v) {
        // nibble->byte: lo = even elems of the 8-group, hi = odd elems
        const unsigned lx = kr[v].x & 0x0F0F0F0Fu, hx = (kr[v].x >> 4) & 0x0F0F0F0Fu;
        const unsigned ly = kr[v].y & 0x0F0F0F0Fu, hy = (kr[v].y >> 4) & 0x0F0F0F0Fu;
        const unsigned lz = kr[v].z & 0x0F0F0F0Fu, hz = (kr[v].z >> 4) & 0x0F0F0F0Fu;
        const unsigned lw = kr[v].w & 0x0F0F0F0Fu, hw = (kr[v].w >> 4) & 0x0F0F0F0Fu;
        int d = sd4((int)qda.x, (int)lx, 0);
        d = sd4((int)qda.y, (int)hx, d);
        d = sd4((int)qda.z, (int)ly, d);
        d = sd4((int)qda.w, (int)hy, d);
        d = sd4((int)qdb.x, (int)lz, d);
        d = sd4((int)qdb.y, (int)hz, d);
        d = sd4((int)qdb.z, (int)lw, d);
        d = sd4((int)qdb.w, (int)hw, d);
        d -= qs << 3;                         // remove +8 bias
        part[u][c4][v * 16 + r16] = (float)d; // |d| < 2^24: exact in fp32
    }
    __builtin_amdgcn_wave_barrier();

    float Lf0 = 0.f, Lf1 = 0.f;               // sums < 2^24: exact
    #pragma unroll
    for (int c = 0; c < 4; ++c) { Lf0 += part[u][c][j]; Lf1 += part[u][c][64 + j]; }
    const float L0 = Lf0 * INV_S48;
    const float L1 = Lf1 * INV_S48;

    // ---- Screening softmax (intra-wave, 2 logits/lane) ----
    float mx = fmaxf(L0, L1);
    #pragma unroll
    for (int o = 32; o; o >>= 1) mx = fmaxf(mx, __shfl_xor(mx, o));
    const float e0 = __expf(L0 - mx), e1 = __expf(L1 - mx);
    float ssum = e0 + e1;
    #pragma unroll
    for (int o = 32; o; o >>= 1) ssum += __shfl_xor(ssum, o);
    const float inv_ssum = 1.f / ssum;

    // ---- Ballot compaction (no atomics) ----
    const unsigned long long mk0 = __ballot(e0 * inv_ssum >= EPS_SCREEN);
    const unsigned long long mk1 = __ballot(e1 * inv_ssum >= EPS_SCREEN);
    const int n0 = __popcll(mk0);
    const int n  = n0 + __popcll(mk1);
    const unsigned long long lt = (j == 0) ? 0ull : (~0ull >> (64 - j));
    if (mk0 & (1ull << j)) widx[u][__popcll(mk0 & lt)]      = cs[u][j];
    if (mk1 & (1ull << j)) widx[u][n0 + __popcll(mk1 & lt)] = cs[u][64 + j];
    __builtin_amdgcn_wave_barrier();

    // ---- Rescore: fp16 K, 8 slots/lane covers n<=32 in registers ----
    const int c16 = j & 15;   // half8 chunk (d = c16*8..+7)
    const int r4  = j >> 4;   // slot group: slots ≡ r4 (mod 4)
    const half8* kb16 = reinterpret_cast<const half8*>(kh + (size_t)b * Nc * Dc);
    const half8* vb16 = reinterpret_cast<const half8*>(vh + (size_t)b * Nc * Dc);
    const half8 qv = *reinterpret_cast<const half8*>(&qsh[u][c16 * 8]);

    float L[8];
    #pragma unroll
    for (int t = 0; t < 8; ++t) {
        const int slot = t * 4 + r4;
        const half8 kx = (slot < n) ? kb16[(size_t)widx[u][slot] * 16 + c16] : half8{};
        L[t] = dot8_f16(qv, kx);
    }
    #pragma unroll
    for (int o = 1; o <= 8; o <<= 1) {
        #pragma unroll
        for (int t = 0; t < 8; ++t) L[t] += __shfl_xor(L[t], o);
    }

    float w[8];
    if (n <= 32) {
        // ---- register softmax: groups own disjoint slot sets -> two hops ----
        float mx2 = -1e30f;
        #pragma unroll
        for (int t = 0; t < 8; ++t) {
            L[t] = (t * 4 + r4 < n) ? L[t] : -1e30f;
            mx2 = fmaxf(mx2, L[t]);
        }
        mx2 = fmaxf(mx2, __shfl_xor(mx2, 16));
        mx2 = fmaxf(mx2, __shfl_xor(mx2, 32));
        float s2 = 0.f;
        #pragma unroll
        for (int t = 0; t < 8; ++t) {
            w[t] = (t * 4 + r4 < n) ? __expf(L[t] - mx2) : 0.f;
            s2 += w[t];
        }
        s2 += __shfl_xor(s2, 16);     // each slot counted exactly once
        s2 += __shfl_xor(s2, 32);
        const float i2 = 1.f / s2;
        #pragma unroll
        for (int t = 0; t < 8; ++t) w[t] *= i2;
    } else {
        // ---- rare fallback (n>32): logits to LDS, exact LDS softmax ----
        if (c16 == 0) {
            #pragma unroll
            for (int t = 0; t < 8; ++t)
                if (t * 4 + r4 < n) lswp[u][t * 4 + r4] = L[t];
        }
        for (int base = 32; base < n; base += 32) {
            float L2[8];
            #pragma unroll
            for (int t = 0; t < 8; ++t) {
                const int slot = base + t * 4 + r4;            // <= 127
                const half8 kx = (slot < n) ? kb16[(size_t)widx[u][slot] * 16 + c16]
                                            : half8{};
                L2[t] = dot8_f16(qv, kx);
            }
            #pragma unroll
            for (int o = 1; o <= 8; o <<= 1) {
                #pragma unroll
                for (int t = 0; t < 8; ++t) L2[t] += __shfl_xor(L2[t], o);
            }
            if (c16 == 0) {
                #pragma unroll
                for (int t = 0; t < 8; ++t)
                    if (base + t * 4 + r4 < n) lswp[u][base + t * 4 + r4] = L2[t];
            }
        }
        __builtin_amdgcn_wave_barrier();
        const float A  = (j < n)      ? lswp[u][j]      : -1e30f;
        const float B2 = (64 + j < n) ? lswp[u][64 + j] : -1e30f;
        float mx2 = fmaxf(A, B2);
        #pragma unroll
        for (int o = 32; o; o >>= 1) mx2 = fmaxf(mx2, __shfl_xor(mx2, o));
        const float ea = (j < n)      ? __expf(A - mx2)  : 0.f;
        const float eb = (64 + j < n) ? __expf(B2 - mx2) : 0.f;
        float s2 = ea + eb;
        #pragma unroll
        for (int o = 32; o; o >>= 1) s2 += __shfl_xor(s2, o);
        const float i2 = 1.f / s2;
        lswp[u][j]      = (j < n)      ? ea * i2 : 0.f;
        lswp[u][64 + j] = (64 + j < n) ? eb * i2 : 0.f;
        __builtin_amdgcn_wave_barrier();
        #pragma unroll
        for (int t = 0; t < 8; ++t) w[t] = (t * 4 + r4 < n) ? lswp[u][t * 4 + r4] : 0.f;
    }

    // ---- V: gathered AFTER softmax, only where weight matters ----
    float acc[8];
    #pragma unroll
    for (int e = 0; e < 8; ++e) acc[e] = 0.f;
    #pragma unroll
    for (int t = 0; t < 8; ++t) {
        if (w[t] >= WEPS) {   // uniform within each 16-lane group
            const half8 vx = vb16[(size_t)widx[u][t * 4 + r4] * 16 + c16];
            #pragma unroll
            for (int e = 0; e < 8; ++e) acc[e] += w[t] * (float)vx[e];
        }
    }
    if (n > 32) {                                   // rare fallback slots
        for (int s = 32 + r4; s < n; s += 4) {
            const float w2 = lswp[u][s];
            if (w2 >= WEPS) {
                const half8 vx = vb16[(size_t)widx[u][s] * 16 + c16];
                #pragma unroll
                for (int e = 0; e < 8; ++e) acc[e] += w2 * (float)vx[e];
            }
        }
    }
    // reduce across the 4 slot groups (same chunk c16 lives at j^16/j^32/j^48)
    #pragma unroll
    for (int e = 0; e < 8; ++e) {
        acc[e] += __shfl_xor(acc[e], 16);
        acc[e] += __shfl_xor(acc[e], 32);
    }
    if (j < 32) {   // lanes 0..15 -> even float4s, 16..31 -> odd float4s
        float4 o4;
        o4.x = r4 ? acc[4] : acc[0];
        o4.y = r4 ? acc[5] : acc[1];
        o4.z = r4 ? acc[6] : acc[2];
        o4.w = r4 ? acc[7] : acc[3];
        reinterpret_cast<float4*>(out + ((size_t)b * Mc + m) * Dc)[2 * c16 + r4] = o4;
    }
}

extern "C" void kernel_launch(void* const* d_in, const int* in_sizes, int n_in,
                              void* d_out, int out_size, void* d_ws, size_t ws_size,
                              hipStream_t stream) {
    const float* q = (const float*)d_in[0];
    const float* k = (const float*)d_in[1];
    const float* v = (const float*)d_in[2];
    const int*   c = (const int*)d_in[3];
    float*       o = (float*)d_out;
    (void)in_sizes; (void)n_in; (void)out_size; (void)ws_size;

    _Float16*     kh  = (_Float16*)d_ws;                                   // 4 MB
    unsigned int* k4p = (unsigned int*)((char*)d_ws + KV_ELEMS * sizeof(_Float16)); // 1 MB
    _Float16*     vh  = (_Float16*)((char*)d_ws + KV_ELEMS * sizeof(_Float16)
                                                 + KV_ELEMS / 2);          // 4 MB

    const int cvt_threads = 256;
    const int cvt_blocks  = (int)(KV_ELEMS / 8 / cvt_threads);   // 1024
    cvt_kernel<<<cvt_blocks, cvt_threads, 0, stream>>>(k, v, kh, k4p, vh);

    sparse_attn_r18<<<dim3(Bc * Mc / 2), dim3(128), 0, stream>>>(q, kh, k4p, vh, c, o);
}